// Round 1
// baseline (8618.360 us; speedup 1.0000x reference)
//
#include <hip/hip_runtime.h>
#include <hip/hip_bf16.h>
#include <math.h>

#define NN 10000
#define NE 100000
#define HH 256
#define SPGc 1250
#define NG 8
#define NL 5
#define CHK 50000

// ---------------- node types ----------------
__global__ __launch_bounds__(256) void k_types(const float* __restrict__ x, int* __restrict__ types) {
    int i = blockIdx.x * 256 + threadIdx.x;
    if (i < NN) {
        float v = rintf(x[(size_t)i * 16 + 2] * 3.0f);   // jnp.round = rint (half-to-even)
        v = fminf(fmaxf(v, 1.0f), 3.0f);
        types[i] = (int)v - 1;
    }
}

// ---------------- CSR build (for segment_sum over dst) ----------------
__global__ __launch_bounds__(256) void k_hist(const int* __restrict__ dst, int* __restrict__ deg) {
    int e = blockIdx.x * 256 + threadIdx.x;
    if (e < NE) atomicAdd(&deg[dst[e]], 1);
}

__global__ __launch_bounds__(256) void k_scan(const int* __restrict__ deg, int* __restrict__ row_ptr,
                                              int* __restrict__ cursor) {
    __shared__ int buf[256];
    int tid = threadIdx.x;
    int base = 0;
    for (int c = 0; c < NN; c += 256) {
        int i = c + tid;
        int v = (i < NN) ? deg[i] : 0;
        buf[tid] = v;
        __syncthreads();
        for (int off = 1; off < 256; off <<= 1) {
            int t = (tid >= off) ? buf[tid - off] : 0;
            __syncthreads();
            buf[tid] += t;
            __syncthreads();
        }
        if (i < NN) {
            row_ptr[i + 1] = base + buf[tid];
            cursor[i] = base + buf[tid] - v;
        }
        __syncthreads();
        base += buf[255];
        __syncthreads();
    }
    if (tid == 0) row_ptr[0] = 0;
}

__global__ __launch_bounds__(256) void k_scatter(const int* __restrict__ dst, int* __restrict__ cursor,
                                                 int* __restrict__ csr) {
    int e = blockIdx.x * 256 + threadIdx.x;
    if (e < NE) {
        int p = atomicAdd(&cursor[dst[e]], 1);
        csr[p] = e;
    }
}

// ---------------- per-type node encoder ----------------
__global__ __launch_bounds__(256) void k_enc(const float* __restrict__ x, const float* __restrict__ pe,
        const int* __restrict__ types,
        const float* __restrict__ w1, const float* __restrict__ b1,
        const float* __restrict__ w2, const float* __restrict__ b2,
        float* __restrict__ h_nodes) {
    int n = blockIdx.x;
    int j = threadIdx.x;
    __shared__ float inp[21];
    __shared__ float hid[256];
    if (j < 16) inp[j] = x[(size_t)n * 16 + j];
    else if (j < 21) inp[j] = pe[(size_t)n * 5 + (j - 16)];
    __syncthreads();
    int t = types[n];
    const float* W1 = w1 + (size_t)t * 21 * 256;
    float a = b1[t * 256 + j];
    #pragma unroll
    for (int i = 0; i < 21; ++i) a = fmaf(inp[i], W1[i * 256 + j], a);
    hid[j] = fmaxf(a, 0.f);
    __syncthreads();
    const float* W2 = w2 + (size_t)t * 256 * 256;
    float o = b2[t * 256 + j];
    for (int k = 0; k < 256; ++k) o = fmaf(hid[k], W2[k * 256 + j], o);
    h_nodes[(size_t)n * 256 + j] = o;
}

// ---------------- generic fp32 GEMM: C[M,Nout] = f(A[M,K] @ W[K,Nout] + b) ----------------
// AMODE 0: A0 + row*lda + k
// AMODE 1: concat(h_nodes[idx0[row]], h_nodes[idx1[row]], A1[row])   (K=768)
// AMODE 2: concat(A0[row], A1[row])                                  (K=512)
template<int AMODE, bool RELU, bool HASRES>
__global__ __launch_bounds__(256) void gemm64(int Mrows, int K, int Nout,
        const float* __restrict__ A0, const float* __restrict__ A1,
        const int* __restrict__ idx0, const int* __restrict__ idx1,
        int lda, int rowOfsA, int rowOfsC,
        const float* __restrict__ W, const float* __restrict__ bias,
        const float* __restrict__ Res, float resScale, float* __restrict__ C) {
    __shared__ __align__(16) float As[16][68];   // [k][row], pad 68 -> conflict-free, 16B-aligned rows
    __shared__ __align__(16) float Ws[16][64];   // [k][col]
    int tid = threadIdx.x;
    int tx = tid & 15, ty = tid >> 4;
    int blockRow = blockIdx.x * 64;
    int ncol0 = blockIdx.y * 64;
    float acc[4][4];
    #pragma unroll
    for (int i = 0; i < 4; ++i)
        #pragma unroll
        for (int j = 0; j < 4; ++j) acc[i][j] = 0.f;

    for (int k0 = 0; k0 < K; k0 += 16) {
        #pragma unroll
        for (int i = 0; i < 4; ++i) {
            int id = tid + 256 * i;
            int kk = id & 15, r = id >> 4;
            int grow = blockRow + r;
            int k = k0 + kk;
            float v = 0.f;
            if (grow < Mrows && k < K) {
                int arow = grow + rowOfsA;
                const float* p;
                if (AMODE == 0) {
                    p = A0 + (size_t)arow * lda + k;
                } else if (AMODE == 1) {
                    if (k < 256)      p = A0 + (size_t)idx0[arow] * 256 + k;
                    else if (k < 512) p = A0 + (size_t)idx1[arow] * 256 + (k - 256);
                    else              p = A1 + (size_t)arow * 256 + (k - 512);
                } else {
                    if (k < 256) p = A0 + (size_t)arow * 256 + k;
                    else         p = A1 + (size_t)arow * 256 + (k - 256);
                }
                v = *p;
            }
            As[kk][r] = v;
        }
        #pragma unroll
        for (int i = 0; i < 4; ++i) {
            int id = tid + 256 * i;
            int c = id & 63, kk = id >> 6;
            int k = k0 + kk;
            Ws[kk][c] = (k < K) ? W[(size_t)k * Nout + ncol0 + c] : 0.f;
        }
        __syncthreads();
        #pragma unroll
        for (int kk = 0; kk < 16; ++kk) {
            const float4 a4 = *(const float4*)&As[kk][ty << 2];
            const float4 w4 = *(const float4*)&Ws[kk][tx << 2];
            float av[4] = {a4.x, a4.y, a4.z, a4.w};
            float wv[4] = {w4.x, w4.y, w4.z, w4.w};
            #pragma unroll
            for (int i = 0; i < 4; ++i)
                #pragma unroll
                for (int j = 0; j < 4; ++j)
                    acc[i][j] = fmaf(av[i], wv[j], acc[i][j]);
        }
        __syncthreads();
    }
    #pragma unroll
    for (int i = 0; i < 4; ++i) {
        int grow = blockRow + (ty << 2) + i;
        if (grow >= Mrows) continue;
        size_t crow = (size_t)(grow + rowOfsC);
        size_t base = crow * Nout + ncol0 + (tx << 2);
        float ov[4];
        #pragma unroll
        for (int j = 0; j < 4; ++j) {
            float v2 = acc[i][j] + bias[ncol0 + (tx << 2) + j];
            if (RELU) v2 = fmaxf(v2, 0.f);
            ov[j] = v2;
        }
        if (HASRES) {
            const float4 rv = *(const float4*)(Res + base);
            ov[0] += resScale * rv.x; ov[1] += resScale * rv.y;
            ov[2] += resScale * rv.z; ov[3] += resScale * rv.w;
        }
        float4 o; o.x = ov[0]; o.y = ov[1]; o.z = ov[2]; o.w = ov[3];
        *(float4*)(C + base) = o;
    }
}

// ---------------- segment-sum gather: m_node[n] = sum_{e: dst[e]==n} h_edges[e] ----------------
__global__ __launch_bounds__(256) void k_mnode(const float* __restrict__ h_edges,
        const int* __restrict__ row_ptr, const int* __restrict__ csr, float* __restrict__ m_node) {
    int n = blockIdx.x * 4 + (threadIdx.x >> 6);
    int lane = threadIdx.x & 63;
    if (n >= NN) return;
    float a0 = 0.f, a1 = 0.f, a2 = 0.f, a3 = 0.f;
    int s = row_ptr[n], e = row_ptr[n + 1];
    for (int i = s; i < e; ++i) {
        int ed = csr[i];
        const float4 v = *(const float4*)(h_edges + (size_t)ed * 256 + (lane << 2));
        a0 += v.x; a1 += v.y; a2 += v.z; a3 += v.w;
    }
    float4 r; r.x = a0; r.y = a1; r.z = a2; r.w = a3;
    *(float4*)(m_node + (size_t)n * 256 + (lane << 2)) = r;
}

// ---------------- flash attention (fp32), per (graph, head, 64 q-rows) ----------------
__global__ __launch_bounds__(256) void k_attn(const float* __restrict__ qkv, float* __restrict__ obuf) {
    int gh = blockIdx.y;
    int g = gh >> 2, h = gh & 3;
    int q0 = blockIdx.x * 64;
    int tid = threadIdx.x;
    int r = tid >> 2, q4 = tid & 3;
    int d0 = q4 * 16;
    __shared__ __align__(16) float Ks[32][64];
    __shared__ __align__(16) float Vs[32][64];
    const float* base = qkv + (size_t)g * SPGc * 768;
    int my_s = q0 + r;
    bool rowok = my_s < SPGc;
    float qreg[16];
    #pragma unroll
    for (int dd = 0; dd < 16; ++dd) qreg[dd] = 0.f;
    if (rowok) {
        const float* qp = base + (size_t)my_s * 768 + h * 64 + d0;
        #pragma unroll
        for (int dd = 0; dd < 16; ++dd) qreg[dd] = qp[dd];
    }
    float m = -1e30f, l = 0.f;
    float oacc[16];
    #pragma unroll
    for (int dd = 0; dd < 16; ++dd) oacc[dd] = 0.f;

    for (int t0 = 0; t0 < SPGc; t0 += 32) {
        #pragma unroll
        for (int i = 0; i < 8; ++i) {
            int id = tid + 256 * i;
            int d = id & 63, jj = id >> 6;
            int s = t0 + jj;
            float kv = 0.f, vv = 0.f;
            if (s < SPGc) {
                const float* kp = base + (size_t)s * 768 + h * 64;
                kv = kp[256 + d];
                vv = kp[512 + d];
            }
            Ks[jj][d] = kv;
            Vs[jj][d] = vv;
        }
        __syncthreads();
        float sc[32];
        #pragma unroll
        for (int j = 0; j < 32; ++j) {
            float p = 0.f;
            #pragma unroll
            for (int dd = 0; dd < 16; dd += 4) {
                const float4 k4 = *(const float4*)&Ks[j][d0 + dd];
                p = fmaf(qreg[dd], k4.x, p);
                p = fmaf(qreg[dd + 1], k4.y, p);
                p = fmaf(qreg[dd + 2], k4.z, p);
                p = fmaf(qreg[dd + 3], k4.w, p);
            }
            sc[j] = p;
        }
        #pragma unroll
        for (int j = 0; j < 32; ++j) {
            float p = sc[j];
            p += __shfl_xor(p, 1);
            p += __shfl_xor(p, 2);
            sc[j] = (t0 + j < SPGc) ? p * 0.125f : -1e30f;
        }
        float mt = sc[0];
        #pragma unroll
        for (int j = 1; j < 32; ++j) mt = fmaxf(mt, sc[j]);
        float mnew = fmaxf(m, mt);
        float f = __expf(m - mnew);
        l *= f;
        #pragma unroll
        for (int dd = 0; dd < 16; ++dd) oacc[dd] *= f;
        #pragma unroll
        for (int j = 0; j < 32; ++j) {
            float p = __expf(sc[j] - mnew);
            l += p;
            #pragma unroll
            for (int dd = 0; dd < 16; dd += 4) {
                const float4 v4 = *(const float4*)&Vs[j][d0 + dd];
                oacc[dd]     = fmaf(p, v4.x, oacc[dd]);
                oacc[dd + 1] = fmaf(p, v4.y, oacc[dd + 1]);
                oacc[dd + 2] = fmaf(p, v4.z, oacc[dd + 2]);
                oacc[dd + 3] = fmaf(p, v4.w, oacc[dd + 3]);
            }
        }
        m = mnew;
        __syncthreads();
    }
    if (rowok) {
        float rinv = 1.0f / l;
        float* op = obuf + (size_t)(g * SPGc + my_s) * 256 + h * 64 + d0;
        #pragma unroll
        for (int dd = 0; dd < 16; ++dd) op[dd] = oacc[dd] * rinv;
    }
}

// ---------------- per-type decoder ----------------
__global__ __launch_bounds__(256) void k_dec(const float* __restrict__ h, const int* __restrict__ types,
        const float* __restrict__ w1, const float* __restrict__ b1,
        const float* __restrict__ w2, const float* __restrict__ b2,
        float* __restrict__ out) {
    int n = blockIdx.x;
    int j = threadIdx.x;
    __shared__ float hrow[256];
    __shared__ float dhid[256];
    hrow[j] = h[(size_t)n * 256 + j];
    __syncthreads();
    int t = types[n];
    const float* W1 = w1 + (size_t)t * 256 * 256;
    float a = b1[t * 256 + j];
    for (int k = 0; k < 256; ++k) a = fmaf(hrow[k], W1[k * 256 + j], a);
    dhid[j] = fmaxf(a, 0.f);
    __syncthreads();
    int lane = j & 63, w = j >> 6;
    const float* W2 = w2 + (size_t)t * 256 * 4;
    float p = 0.f;
    #pragma unroll
    for (int q = 0; q < 4; ++q) {
        int kk = lane + 64 * q;
        p = fmaf(dhid[kk], W2[kk * 4 + w], p);
    }
    #pragma unroll
    for (int o2 = 32; o2 > 0; o2 >>= 1) p += __shfl_down(p, o2);
    if (lane == 0) out[(size_t)n * 4 + w] = p + b2[t * 4 + w];
}

extern "C" void kernel_launch(void* const* d_in, const int* in_sizes, int n_in,
                              void* d_out, int out_size, void* d_ws, size_t ws_size,
                              hipStream_t stream) {
    const float* x         = (const float*)d_in[0];
    const float* pe        = (const float*)d_in[1];
    const float* edge_attr = (const float*)d_in[2];
    const int*   eidx      = (const int*)d_in[3];
    const float* enc_w1 = (const float*)d_in[5];
    const float* enc_b1 = (const float*)d_in[6];
    const float* enc_w2 = (const float*)d_in[7];
    const float* enc_b2 = (const float*)d_in[8];
    const float* ee_w1  = (const float*)d_in[9];
    const float* ee_b1  = (const float*)d_in[10];
    const float* ee_w2  = (const float*)d_in[11];
    const float* ee_b2  = (const float*)d_in[12];
    const float* eu_w1  = (const float*)d_in[13];
    const float* eu_b1  = (const float*)d_in[14];
    const float* eu_w2  = (const float*)d_in[15];
    const float* eu_b2  = (const float*)d_in[16];
    const float* nu_w1  = (const float*)d_in[17];
    const float* nu_b1  = (const float*)d_in[18];
    const float* nu_w2  = (const float*)d_in[19];
    const float* nu_b2  = (const float*)d_in[20];
    const float* qkv_w  = (const float*)d_in[21];
    const float* qkv_b  = (const float*)d_in[22];
    const float* out_w  = (const float*)d_in[23];
    const float* out_b  = (const float*)d_in[24];
    const float* fu_w1  = (const float*)d_in[25];
    const float* fu_b1  = (const float*)d_in[26];
    const float* fu_w2  = (const float*)d_in[27];
    const float* fu_b2  = (const float*)d_in[28];
    const float* dec_w1 = (const float*)d_in[29];
    const float* dec_b1 = (const float*)d_in[30];
    const float* dec_w2 = (const float*)d_in[31];
    const float* dec_b2 = (const float*)d_in[32];

    const int* src  = eidx;
    const int* dstp = eidx + NE;

    float* ws = (float*)d_ws;
    size_t off = 0;
    float* h_edges = ws + off; off += (size_t)NE * HH;    // 25.6M floats
    float* big     = ws + off; off += (size_t)CHK * HH;   // 12.8M floats (>= NN*768 for qkv)
    float* h_nodes = ws + off; off += (size_t)NN * HH;
    float* m_node  = ws + off; off += (size_t)NN * HH;    // also reused as `fin`
    float* nhid    = ws + off; off += (size_t)NN * HH;
    float* obuf    = ws + off; off += (size_t)NN * HH;    // attn out, then h_fused
    int* ibase  = (int*)(ws + off);
    int* types   = ibase;
    int* deg     = ibase + NN;
    int* row_ptr = deg + NN;
    int* cursor  = row_ptr + NN + 1;
    int* csr     = cursor + NN;

    hipMemsetAsync(deg, 0, NN * sizeof(int), stream);
    k_types<<<(NN + 255) / 256, 256, 0, stream>>>(x, types);
    k_hist<<<(NE + 255) / 256, 256, 0, stream>>>(dstp, deg);
    k_scan<<<1, 256, 0, stream>>>(deg, row_ptr, cursor);
    k_scatter<<<(NE + 255) / 256, 256, 0, stream>>>(dstp, cursor, csr);
    k_enc<<<NN, 256, 0, stream>>>(x, pe, types, enc_w1, enc_b1, enc_w2, enc_b2, h_nodes);

    // edge encoder
    for (int c0 = 0; c0 < NE; c0 += CHK) {
        int m = (NE - c0 < CHK) ? NE - c0 : CHK;
        dim3 grid((m + 63) / 64, 4);
        gemm64<0, true, false><<<grid, 256, 0, stream>>>(m, 8, 256, edge_attr, nullptr, nullptr, nullptr,
            8, c0, 0, ee_w1, ee_b1, nullptr, 0.f, big);
        gemm64<0, false, false><<<grid, 256, 0, stream>>>(m, 256, 256, big, nullptr, nullptr, nullptr,
            256, 0, c0, ee_w2, ee_b2, nullptr, 0.f, h_edges);
    }

    // message-passing layers
    for (int l = 0; l < NL; ++l) {
        for (int c0 = 0; c0 < NE; c0 += CHK) {
            int m = (NE - c0 < CHK) ? NE - c0 : CHK;
            dim3 grid((m + 63) / 64, 4);
            gemm64<1, true, false><<<grid, 256, 0, stream>>>(m, 768, 256, h_nodes, h_edges, src, dstp,
                0, c0, 0, eu_w1 + (size_t)l * 768 * 256, eu_b1 + l * 256, nullptr, 0.f, big);
            gemm64<0, false, true><<<grid, 256, 0, stream>>>(m, 256, 256, big, nullptr, nullptr, nullptr,
                256, 0, c0, eu_w2 + (size_t)l * 256 * 256, eu_b2 + l * 256, h_edges, 1.f, h_edges);
        }
        k_mnode<<<(NN + 3) / 4, 256, 0, stream>>>(h_edges, row_ptr, csr, m_node);
        dim3 gnode((NN + 63) / 64, 4);
        gemm64<2, true, false><<<gnode, 256, 0, stream>>>(NN, 512, 256, h_nodes, m_node, nullptr, nullptr,
            0, 0, 0, nu_w1 + (size_t)l * 512 * 256, nu_b1 + l * 256, nullptr, 0.f, nhid);
        gemm64<0, false, true><<<gnode, 256, 0, stream>>>(NN, 256, 256, nhid, nullptr, nullptr, nullptr,
            256, 0, 0, nu_w2 + (size_t)l * 256 * 256, nu_b2 + l * 256, h_nodes, 1.f, h_nodes);
    }

    // global attention
    dim3 gq((NN + 63) / 64, 12);
    gemm64<0, false, false><<<gq, 256, 0, stream>>>(NN, 256, 768, h_nodes, nullptr, nullptr, nullptr,
        256, 0, 0, qkv_w, qkv_b, nullptr, 0.f, big);
    dim3 ga((SPGc + 63) / 64, NG * 4);
    k_attn<<<ga, 256, 0, stream>>>(big, obuf);

    // out-proj + residuals + fusion MLP:  fin = 2*h_nodes + o@out_w + out_b ; h = relu(fin@fu_w1+b)@fu_w2+b
    dim3 gf((NN + 63) / 64, 4);
    gemm64<0, false, true><<<gf, 256, 0, stream>>>(NN, 256, 256, obuf, nullptr, nullptr, nullptr,
        256, 0, 0, out_w, out_b, h_nodes, 2.f, m_node);
    gemm64<0, true, false><<<gf, 256, 0, stream>>>(NN, 256, 256, m_node, nullptr, nullptr, nullptr,
        256, 0, 0, fu_w1, fu_b1, nullptr, 0.f, nhid);
    gemm64<0, false, false><<<gf, 256, 0, stream>>>(NN, 256, 256, nhid, nullptr, nullptr, nullptr,
        256, 0, 0, fu_w2, fu_b2, nullptr, 0.f, obuf);

    k_dec<<<NN, 256, 0, stream>>>(obuf, types, dec_w1, dec_b1, dec_w2, dec_b2, (float*)d_out);
}

// Round 7
// 4436.113 us; speedup vs baseline: 1.9428x; 1.9428x over previous
//
#include <hip/hip_runtime.h>
#include <hip/hip_bf16.h>
#include <math.h>

#define NN 10000
#define NE 100000
#define SPGc 1250
#define NG 8
#define NL 5
#define ECHK 25000

__device__ __forceinline__ int imin(int a, int b) { return a < b ? a : b; }

// ---------------- node types ----------------
__global__ __launch_bounds__(256) void k_types(const float* __restrict__ x, int* __restrict__ types) {
    int i = blockIdx.x * 256 + threadIdx.x;
    if (i < NN) {
        float v = rintf(x[(size_t)i * 16 + 2] * 3.0f);
        v = fminf(fmaxf(v, 1.0f), 3.0f);
        types[i] = (int)v - 1;
    }
}

// ---------------- CSR build ----------------
__global__ __launch_bounds__(256) void k_hist(const int* __restrict__ dst, int* __restrict__ deg) {
    int e = blockIdx.x * 256 + threadIdx.x;
    if (e < NE) atomicAdd(&deg[dst[e]], 1);
}

__global__ __launch_bounds__(256) void k_scan(const int* __restrict__ deg, int* __restrict__ row_ptr,
                                              int* __restrict__ cursor) {
    __shared__ int buf[256];
    int tid = threadIdx.x;
    int base = 0;
    for (int c = 0; c < NN; c += 256) {
        int i = c + tid;
        int v = (i < NN) ? deg[i] : 0;
        buf[tid] = v;
        __syncthreads();
        for (int off = 1; off < 256; off <<= 1) {
            int t = (tid >= off) ? buf[tid - off] : 0;
            __syncthreads();
            buf[tid] += t;
            __syncthreads();
        }
        if (i < NN) {
            row_ptr[i + 1] = base + buf[tid];
            cursor[i] = base + buf[tid] - v;
        }
        __syncthreads();
        base += buf[255];
        __syncthreads();
    }
    if (tid == 0) row_ptr[0] = 0;
}

__global__ __launch_bounds__(256) void k_scatter(const int* __restrict__ dst, int* __restrict__ cursor,
                                                 int* __restrict__ csr) {
    int e = blockIdx.x * 256 + threadIdx.x;
    if (e < NE) {
        int p = atomicAdd(&cursor[dst[e]], 1);
        csr[p] = e;
    }
}

// ---------------- per-type node encoder (fp32) ----------------
__global__ __launch_bounds__(256) void k_enc(const float* __restrict__ x, const float* __restrict__ pe,
        const int* __restrict__ types,
        const float* __restrict__ w1, const float* __restrict__ b1,
        const float* __restrict__ w2, const float* __restrict__ b2,
        float* __restrict__ h_nodes) {
    int n = blockIdx.x;
    int j = threadIdx.x;
    __shared__ float inp[21];
    __shared__ float hid[256];
    if (j < 16) inp[j] = x[(size_t)n * 16 + j];
    else if (j < 21) inp[j] = pe[(size_t)n * 5 + (j - 16)];
    __syncthreads();
    int t = types[n];
    const float* W1 = w1 + (size_t)t * 21 * 256;
    float a = b1[t * 256 + j];
    #pragma unroll
    for (int i = 0; i < 21; ++i) a = fmaf(inp[i], W1[i * 256 + j], a);
    hid[j] = fmaxf(a, 0.f);
    __syncthreads();
    const float* W2 = w2 + (size_t)t * 256 * 256;
    float o = b2[t * 256 + j];
    for (int k = 0; k < 256; ++k) o = fmaf(hid[k], W2[k * 256 + j], o);
    h_nodes[(size_t)n * 256 + j] = o;
}

// ---------------- small fp32 GEMM (edge encoder layer 1, K=8), relu, fp32 out ----------------
__global__ __launch_bounds__(256) void gemm64(int Mrows, int K, int Nout,
        const float* __restrict__ A0, int lda,
        const float* __restrict__ W, const float* __restrict__ bias,
        float* __restrict__ C) {
    __shared__ __align__(16) float As[16][68];
    __shared__ __align__(16) float Ws[16][64];
    int tid = threadIdx.x;
    int tx = tid & 15, ty = tid >> 4;
    int blockRow = blockIdx.x * 64;
    int ncol0 = blockIdx.y * 64;
    float acc[4][4];
    #pragma unroll
    for (int i = 0; i < 4; ++i)
        #pragma unroll
        for (int j = 0; j < 4; ++j) acc[i][j] = 0.f;

    for (int k0 = 0; k0 < K; k0 += 16) {
        #pragma unroll
        for (int i = 0; i < 4; ++i) {
            int id = tid + 256 * i;
            int kk = id & 15, r = id >> 4;
            int grow = blockRow + r;
            int k = k0 + kk;
            float v = 0.f;
            if (grow < Mrows && k < K) v = A0[(size_t)grow * lda + k];
            As[kk][r] = v;
        }
        #pragma unroll
        for (int i = 0; i < 4; ++i) {
            int id = tid + 256 * i;
            int c = id & 63, kk = id >> 6;
            int k = k0 + kk;
            Ws[kk][c] = (k < K) ? W[(size_t)k * Nout + ncol0 + c] : 0.f;
        }
        __syncthreads();
        #pragma unroll
        for (int kk = 0; kk < 16; ++kk) {
            const float4 a4 = *(const float4*)&As[kk][ty << 2];
            const float4 w4 = *(const float4*)&Ws[kk][tx << 2];
            float av[4] = {a4.x, a4.y, a4.z, a4.w};
            float wv[4] = {w4.x, w4.y, w4.z, w4.w};
            #pragma unroll
            for (int i = 0; i < 4; ++i)
                #pragma unroll
                for (int j = 0; j < 4; ++j)
                    acc[i][j] = fmaf(av[i], wv[j], acc[i][j]);
        }
        __syncthreads();
    }
    #pragma unroll
    for (int i = 0; i < 4; ++i) {
        int grow = blockRow + (ty << 2) + i;
        if (grow >= Mrows) continue;
        size_t base = (size_t)grow * Nout + ncol0 + (tx << 2);
        #pragma unroll
        for (int j = 0; j < 4; ++j)
            C[base + j] = fmaxf(acc[i][j] + bias[ncol0 + (tx << 2) + j], 0.f);
    }
}

// ---------------- main fp32 GEMM: BM=64, BN=256, BK=16, 256 threads, 4x16 per thread ----------------
// AMODE 0: A = A0[(row+rowOfsA)*lda + k]
// AMODE 2: A = concat(A0[row+rowOfsA], A1[row+rowOfsA]) (K=512, both lda 256)
// PGATH: epilogue adds Pa[gsrc[row+rowOfsA]] + Pb[gdst[row+rowOfsA]] (Nout==256 assumed)
// HASRES: after relu-position, v += resScale * ResF[crow*Nout+col]
template<int AMODE, bool RELU, bool HASRES, bool PGATH, bool HASBIAS>
__global__ __launch_bounds__(256) void gemm_f32(int Mrows, int K, int Nout,
        const float* __restrict__ A0, const float* __restrict__ A1, int lda, int rowOfsA,
        const int* __restrict__ gsrc, const int* __restrict__ gdst,
        const float* __restrict__ Pa, const float* __restrict__ Pb,
        const float* __restrict__ W, const float* __restrict__ bias,
        const float* __restrict__ ResF, float resScale, int rowOfsC,
        float* __restrict__ C) {
    __shared__ __align__(16) float As[16][68];
    __shared__ __align__(16) float Ws[16][16][20];   // [k][colgroup][16 used of 20]
    int tid = threadIdx.x;
    int blockRow = blockIdx.x * 64;
    int ncol0 = blockIdx.y * 256;
    int r4 = tid >> 4, c16 = tid & 15;
    int sar = tid >> 2, sak = (tid & 3) * 4;         // A staging: row, k-chunk
    int swk = tid >> 4, scg = tid & 15;              // W staging: k, col-group
    float acc[4][16];
    #pragma unroll
    for (int i = 0; i < 4; ++i)
        #pragma unroll
        for (int n = 0; n < 16; ++n) acc[i][n] = 0.f;

    for (int k0 = 0; k0 < K; k0 += 16) {
        // ---- stage A (64 x 16) ----
        {
            int arow = imin(blockRow + sar, Mrows - 1) + rowOfsA;
            float4 av;
            if (AMODE == 0) {
                av = *(const float4*)(A0 + (size_t)arow * lda + k0 + sak);
            } else {
                int k = k0 + sak;
                av = (k < 256) ? *(const float4*)(A0 + (size_t)arow * 256 + k)
                               : *(const float4*)(A1 + (size_t)arow * 256 + (k - 256));
            }
            As[sak + 0][sar] = av.x;
            As[sak + 1][sar] = av.y;
            As[sak + 2][sar] = av.z;
            As[sak + 3][sar] = av.w;
        }
        // ---- stage W (16 x 256) ----
        {
            const float* wp = W + (size_t)(k0 + swk) * Nout + ncol0 + scg * 16;
            *(float4*)&Ws[swk][scg][0]  = *(const float4*)(wp + 0);
            *(float4*)&Ws[swk][scg][4]  = *(const float4*)(wp + 4);
            *(float4*)&Ws[swk][scg][8]  = *(const float4*)(wp + 8);
            *(float4*)&Ws[swk][scg][12] = *(const float4*)(wp + 12);
        }
        __syncthreads();
        #pragma unroll
        for (int kk = 0; kk < 16; ++kk) {
            const float4 a4 = *(const float4*)&As[kk][r4 << 2];
            float av[4] = {a4.x, a4.y, a4.z, a4.w};
            #pragma unroll
            for (int q = 0; q < 4; ++q) {
                const float4 w4 = *(const float4*)&Ws[kk][c16][q << 2];
                float wv[4] = {w4.x, w4.y, w4.z, w4.w};
                #pragma unroll
                for (int i = 0; i < 4; ++i)
                    #pragma unroll
                    for (int j = 0; j < 4; ++j)
                        acc[i][q * 4 + j] = fmaf(av[i], wv[j], acc[i][q * 4 + j]);
            }
        }
        __syncthreads();
    }
    // ---- epilogue ----
    #pragma unroll
    for (int i = 0; i < 4; ++i) {
        int grow = blockRow + (r4 << 2) + i;
        if (grow >= Mrows) continue;
        size_t crow = (size_t)(grow + rowOfsC);
        int colb = ncol0 + (c16 << 4);
        const float* par = nullptr;
        const float* pbr = nullptr;
        if (PGATH) {
            int e = grow + rowOfsA;
            par = Pa + (size_t)gsrc[e] * 256 + colb;
            pbr = Pb + (size_t)gdst[e] * 256 + colb;
        }
        #pragma unroll
        for (int q = 0; q < 4; ++q) {
            float v[4];
            #pragma unroll
            for (int j = 0; j < 4; ++j) v[j] = acc[i][q * 4 + j];
            if (HASBIAS) {
                const float4 b4 = *(const float4*)(bias + colb + q * 4);
                v[0] += b4.x; v[1] += b4.y; v[2] += b4.z; v[3] += b4.w;
            }
            if (PGATH) {
                const float4 pa4 = *(const float4*)(par + q * 4);
                const float4 pb4 = *(const float4*)(pbr + q * 4);
                v[0] += pa4.x + pb4.x; v[1] += pa4.y + pb4.y;
                v[2] += pa4.z + pb4.z; v[3] += pa4.w + pb4.w;
            }
            if (RELU) {
                v[0] = fmaxf(v[0], 0.f); v[1] = fmaxf(v[1], 0.f);
                v[2] = fmaxf(v[2], 0.f); v[3] = fmaxf(v[3], 0.f);
            }
            if (HASRES) {
                const float4 rv = *(const float4*)(ResF + crow * Nout + colb + q * 4);
                v[0] += resScale * rv.x; v[1] += resScale * rv.y;
                v[2] += resScale * rv.z; v[3] += resScale * rv.w;
            }
            float4 o; o.x = v[0]; o.y = v[1]; o.z = v[2]; o.w = v[3];
            *(float4*)(C + crow * Nout + colb + q * 4) = o;
        }
    }
}

// ---------------- segment-sum: m_node[n] = sum_e h_edges[e] (fp32) ----------------
__global__ __launch_bounds__(256) void k_mnode(const float* __restrict__ h_edges,
        const int* __restrict__ row_ptr, const int* __restrict__ csr, float* __restrict__ m_node) {
    int n = blockIdx.x * 4 + (threadIdx.x >> 6);
    int lane = threadIdx.x & 63;
    if (n >= NN) return;
    float a0 = 0.f, a1 = 0.f, a2 = 0.f, a3 = 0.f;
    int s = row_ptr[n], e = row_ptr[n + 1];
    for (int i = s; i < e; ++i) {
        int ed = csr[i];
        const float4 v = *(const float4*)(h_edges + (size_t)ed * 256 + (lane << 2));
        a0 += v.x; a1 += v.y; a2 += v.z; a3 += v.w;
    }
    float4 r; r.x = a0; r.y = a1; r.z = a2; r.w = a3;
    *(float4*)(m_node + (size_t)n * 256 + (lane << 2)) = r;
}

// ---------------- flash attention (fp32 in/out) ----------------
__global__ __launch_bounds__(256) void k_attn(const float* __restrict__ qkv, float* __restrict__ obuf) {
    int gh = blockIdx.y;
    int g = gh >> 2, h = gh & 3;
    int q0 = blockIdx.x * 64;
    int tid = threadIdx.x;
    int r = tid >> 2, q4 = tid & 3;
    int d0 = q4 * 16;
    __shared__ __align__(16) float Ks[32][64];
    __shared__ __align__(16) float Vs[32][64];
    const float* base = qkv + (size_t)g * SPGc * 768;
    int my_s = q0 + r;
    bool rowok = my_s < SPGc;
    float qreg[16];
    #pragma unroll
    for (int dd = 0; dd < 16; ++dd) qreg[dd] = 0.f;
    if (rowok) {
        const float* qp = base + (size_t)my_s * 768 + h * 64 + d0;
        #pragma unroll
        for (int dd = 0; dd < 16; ++dd) qreg[dd] = qp[dd];
    }
    float m = -1e30f, l = 0.f;
    float oacc[16];
    #pragma unroll
    for (int dd = 0; dd < 16; ++dd) oacc[dd] = 0.f;

    for (int t0 = 0; t0 < SPGc; t0 += 32) {
        #pragma unroll
        for (int i = 0; i < 8; ++i) {
            int id = tid + 256 * i;
            int d = id & 63, jj = id >> 6;
            int s = t0 + jj;
            float kv = 0.f, vv = 0.f;
            if (s < SPGc) {
                const float* kp = base + (size_t)s * 768 + h * 64;
                kv = kp[256 + d];
                vv = kp[512 + d];
            }
            Ks[jj][d] = kv;
            Vs[jj][d] = vv;
        }
        __syncthreads();
        float sc[32];
        #pragma unroll
        for (int j = 0; j < 32; ++j) {
            float p = 0.f;
            #pragma unroll
            for (int dd = 0; dd < 16; dd += 4) {
                const float4 k4 = *(const float4*)&Ks[j][d0 + dd];
                p = fmaf(qreg[dd], k4.x, p);
                p = fmaf(qreg[dd + 1], k4.y, p);
                p = fmaf(qreg[dd + 2], k4.z, p);
                p = fmaf(qreg[dd + 3], k4.w, p);
            }
            sc[j] = p;
        }
        #pragma unroll
        for (int j = 0; j < 32; ++j) {
            float p = sc[j];
            p += __shfl_xor(p, 1);
            p += __shfl_xor(p, 2);
            sc[j] = (t0 + j < SPGc) ? p * 0.125f : -1e30f;
        }
        float mt = sc[0];
        #pragma unroll
        for (int j = 1; j < 32; ++j) mt = fmaxf(mt, sc[j]);
        float mnew = fmaxf(m, mt);
        float f = __expf(m - mnew);
        l *= f;
        #pragma unroll
        for (int dd = 0; dd < 16; ++dd) oacc[dd] *= f;
        #pragma unroll
        for (int j = 0; j < 32; ++j) {
            float p = __expf(sc[j] - mnew);
            l += p;
            #pragma unroll
            for (int dd = 0; dd < 16; dd += 4) {
                const float4 v4 = *(const float4*)&Vs[j][d0 + dd];
                oacc[dd]     = fmaf(p, v4.x, oacc[dd]);
                oacc[dd + 1] = fmaf(p, v4.y, oacc[dd + 1]);
                oacc[dd + 2] = fmaf(p, v4.z, oacc[dd + 2]);
                oacc[dd + 3] = fmaf(p, v4.w, oacc[dd + 3]);
            }
        }
        m = mnew;
        __syncthreads();
    }
    if (rowok) {
        float rinv = 1.0f / l;
        float* op = obuf + (size_t)(g * SPGc + my_s) * 256 + h * 64 + d0;
        #pragma unroll
        for (int dd = 0; dd < 16; ++dd) op[dd] = oacc[dd] * rinv;
    }
}

// ---------------- per-type decoder (fp32 in) ----------------
__global__ __launch_bounds__(256) void k_dec(const float* __restrict__ h, const int* __restrict__ types,
        const float* __restrict__ w1, const float* __restrict__ b1,
        const float* __restrict__ w2, const float* __restrict__ b2,
        float* __restrict__ out) {
    int n = blockIdx.x;
    int j = threadIdx.x;
    __shared__ float hrow[256];
    __shared__ float dhid[256];
    hrow[j] = h[(size_t)n * 256 + j];
    __syncthreads();
    int t = types[n];
    const float* W1 = w1 + (size_t)t * 256 * 256;
    float a = b1[t * 256 + j];
    for (int k = 0; k < 256; ++k) a = fmaf(hrow[k], W1[k * 256 + j], a);
    dhid[j] = fmaxf(a, 0.f);
    __syncthreads();
    int lane = j & 63, w = j >> 6;
    const float* W2 = w2 + (size_t)t * 256 * 4;
    float p = 0.f;
    #pragma unroll
    for (int q = 0; q < 4; ++q) {
        int kk = lane + 64 * q;
        p = fmaf(dhid[kk], W2[kk * 4 + w], p);
    }
    #pragma unroll
    for (int o2 = 32; o2 > 0; o2 >>= 1) p += __shfl_down(p, o2);
    if (lane == 0) out[(size_t)n * 4 + w] = p + b2[t * 4 + w];
}

extern "C" void kernel_launch(void* const* d_in, const int* in_sizes, int n_in,
                              void* d_out, int out_size, void* d_ws, size_t ws_size,
                              hipStream_t stream) {
    const float* x         = (const float*)d_in[0];
    const float* pe        = (const float*)d_in[1];
    const float* edge_attr = (const float*)d_in[2];
    const int*   eidx      = (const int*)d_in[3];
    const float* enc_w1 = (const float*)d_in[5];
    const float* enc_b1 = (const float*)d_in[6];
    const float* enc_w2 = (const float*)d_in[7];
    const float* enc_b2 = (const float*)d_in[8];
    const float* ee_w1  = (const float*)d_in[9];
    const float* ee_b1  = (const float*)d_in[10];
    const float* ee_w2  = (const float*)d_in[11];
    const float* ee_b2  = (const float*)d_in[12];
    const float* eu_w1  = (const float*)d_in[13];
    const float* eu_b1  = (const float*)d_in[14];
    const float* eu_w2  = (const float*)d_in[15];
    const float* eu_b2  = (const float*)d_in[16];
    const float* nu_w1  = (const float*)d_in[17];
    const float* nu_b1  = (const float*)d_in[18];
    const float* nu_w2  = (const float*)d_in[19];
    const float* nu_b2  = (const float*)d_in[20];
    const float* qkv_w  = (const float*)d_in[21];
    const float* qkv_b  = (const float*)d_in[22];
    const float* out_w  = (const float*)d_in[23];
    const float* out_b  = (const float*)d_in[24];
    const float* fu_w1  = (const float*)d_in[25];
    const float* fu_b1  = (const float*)d_in[26];
    const float* fu_w2  = (const float*)d_in[27];
    const float* fu_b2  = (const float*)d_in[28];
    const float* dec_w1 = (const float*)d_in[29];
    const float* dec_b1 = (const float*)d_in[30];
    const float* dec_w2 = (const float*)d_in[31];
    const float* dec_b2 = (const float*)d_in[32];

    const int* src  = eidx;
    const int* dstp = eidx + NE;

    float* ws = (float*)d_ws;
    float* h_edges = ws;                       // 25.6M f
    float* big     = ws + 25600000;            // 11.52M f region
    float* h_nodes = ws + 37120000;            // 2.56M f
    float* mn_ob   = ws + 39680000;            // 2.56M f (m_node -> obuf -> hfused)
    float* nhid    = ws + 42240000;            // 2.56M f
    int* ibase   = (int*)(ws + 44800000);
    int* types   = ibase;
    int* deg     = ibase + NN;
    int* row_ptr = deg + NN;
    int* cursor  = row_ptr + NN + 1;
    int* csr     = cursor + NN;

    // big region overlays (phase-disjoint):
    float* ehid = big;                 // [ECHK][256] = 6.4M f (layer phase)
    float* Pa   = big + 6400000;       // 2.56M f (layer phase)
    float* Pb   = big + 8960000;       // 2.56M f (layer phase)
    float* qkvf = big;                 // [NN][768] = 7.68M f (attention phase)
    float* fin  = big + 7680000;       // 2.56M f (fusion phase)

    hipMemsetAsync(deg, 0, NN * sizeof(int), stream);
    k_types<<<(NN + 255) / 256, 256, 0, stream>>>(x, types);
    k_hist<<<(NE + 255) / 256, 256, 0, stream>>>(dstp, deg);
    k_scan<<<1, 256, 0, stream>>>(deg, row_ptr, cursor);
    k_scatter<<<(NE + 255) / 256, 256, 0, stream>>>(dstp, cursor, csr);

    k_enc<<<NN, 256, 0, stream>>>(x, pe, types, enc_w1, enc_b1, enc_w2, enc_b2, h_nodes);

    dim3 gE((ECHK + 63) / 64, 1);
    dim3 gN((NN + 63) / 64, 1);

    // edge encoder (chunked): ehid = relu(edge_attr@ee_w1+b); h_edges = ehid@ee_w2+b
    for (int c0 = 0; c0 < NE; c0 += ECHK) {
        gemm64<<<dim3((ECHK + 63) / 64, 4), 256, 0, stream>>>(ECHK, 8, 256,
            edge_attr + (size_t)c0 * 8, 8, ee_w1, ee_b1, ehid);
        gemm_f32<0, false, false, false, true><<<gE, 256, 0, stream>>>(ECHK, 256, 256,
            ehid, nullptr, 256, 0, nullptr, nullptr, nullptr, nullptr,
            ee_w2, ee_b2, nullptr, 0.f, c0, h_edges);
    }

    // message-passing layers
    for (int l = 0; l < NL; ++l) {
        const float* W1 = eu_w1 + (size_t)l * 768 * 256;
        // Pa = h_nodes @ W1[0:256], Pb = h_nodes @ W1[256:512]   (no bias, no relu)
        gemm_f32<0, false, false, false, false><<<gN, 256, 0, stream>>>(NN, 256, 256,
            h_nodes, nullptr, 256, 0, nullptr, nullptr, nullptr, nullptr,
            W1, nullptr, nullptr, 0.f, 0, Pa);
        gemm_f32<0, false, false, false, false><<<gN, 256, 0, stream>>>(NN, 256, 256,
            h_nodes, nullptr, 256, 0, nullptr, nullptr, nullptr, nullptr,
            W1 + 65536, nullptr, nullptr, 0.f, 0, Pb);
        for (int c0 = 0; c0 < NE; c0 += ECHK) {
            // ehid = relu(h_edges@W1c + Pa[src] + Pb[dst] + b1)
            gemm_f32<0, true, false, true, true><<<gE, 256, 0, stream>>>(ECHK, 256, 256,
                h_edges, nullptr, 256, c0, src, dstp, Pa, Pb,
                W1 + 131072, eu_b1 + l * 256, nullptr, 0.f, 0, ehid);
            // h_edges += ehid@W2 + b2
            gemm_f32<0, false, true, false, true><<<gE, 256, 0, stream>>>(ECHK, 256, 256,
                ehid, nullptr, 256, 0, nullptr, nullptr, nullptr, nullptr,
                eu_w2 + (size_t)l * 65536, eu_b2 + l * 256, h_edges, 1.f, c0, h_edges);
        }
        k_mnode<<<(NN + 3) / 4, 256, 0, stream>>>(h_edges, row_ptr, csr, mn_ob);
        // nhid = relu(concat(h_nodes, m_node)@nu_w1 + b)
        gemm_f32<2, true, false, false, true><<<gN, 256, 0, stream>>>(NN, 512, 256,
            h_nodes, mn_ob, 256, 0, nullptr, nullptr, nullptr, nullptr,
            nu_w1 + (size_t)l * 131072, nu_b1 + l * 256, nullptr, 0.f, 0, nhid);
        // h_nodes += nhid@nu_w2 + b
        gemm_f32<0, false, true, false, true><<<gN, 256, 0, stream>>>(NN, 256, 256,
            nhid, nullptr, 256, 0, nullptr, nullptr, nullptr, nullptr,
            nu_w2 + (size_t)l * 65536, nu_b2 + l * 256, h_nodes, 1.f, 0, h_nodes);
    }

    // qkv projection (fp32)
    gemm_f32<0, false, false, false, true><<<dim3((NN + 63) / 64, 3), 256, 0, stream>>>(NN, 256, 768,
        h_nodes, nullptr, 256, 0, nullptr, nullptr, nullptr, nullptr,
        qkv_w, qkv_b, nullptr, 0.f, 0, qkvf);

    dim3 ga((SPGc + 63) / 64, NG * 4);
    k_attn<<<ga, 256, 0, stream>>>(qkvf, mn_ob);

    // fin = obuf@out_w + out_b + 2*h_nodes ; nhid = relu(fin@fu_w1+b) ; hfused = nhid@fu_w2+b
    gemm_f32<0, false, true, false, true><<<gN, 256, 0, stream>>>(NN, 256, 256,
        mn_ob, nullptr, 256, 0, nullptr, nullptr, nullptr, nullptr,
        out_w, out_b, h_nodes, 2.f, 0, fin);
    gemm_f32<0, true, false, false, true><<<gN, 256, 0, stream>>>(NN, 256, 256,
        fin, nullptr, 256, 0, nullptr, nullptr, nullptr, nullptr,
        fu_w1, fu_b1, nullptr, 0.f, 0, nhid);
    gemm_f32<0, false, false, false, true><<<gN, 256, 0, stream>>>(NN, 256, 256,
        nhid, nullptr, 256, 0, nullptr, nullptr, nullptr, nullptr,
        fu_w2, fu_b2, nullptr, 0.f, 0, mn_ob);

    k_dec<<<NN, 256, 0, stream>>>(mn_ob, types, dec_w1, dec_b1, dec_w2, dec_b2, (float*)d_out);
}

// Round 8
// 4200.486 us; speedup vs baseline: 2.0518x; 1.0561x over previous
//
#include <hip/hip_runtime.h>
#include <hip/hip_bf16.h>
#include <math.h>

#define NN 10000
#define NE 100000
#define SPGc 1250
#define NG 8
#define NL 5
#define ECHK 25000
#define NROWS_A (NG * 4 * SPGc)   // 40000 (g,h,s) rows

__device__ __forceinline__ int imin(int a, int b) { return a < b ? a : b; }

// ---------------- node types ----------------
__global__ __launch_bounds__(256) void k_types(const float* __restrict__ x, int* __restrict__ types) {
    int i = blockIdx.x * 256 + threadIdx.x;
    if (i < NN) {
        float v = rintf(x[(size_t)i * 16 + 2] * 3.0f);
        v = fminf(fmaxf(v, 1.0f), 3.0f);
        types[i] = (int)v - 1;
    }
}

// ---------------- CSR build ----------------
__global__ __launch_bounds__(256) void k_hist(const int* __restrict__ dst, int* __restrict__ deg) {
    int e = blockIdx.x * 256 + threadIdx.x;
    if (e < NE) atomicAdd(&deg[dst[e]], 1);
}

__global__ __launch_bounds__(256) void k_scan(const int* __restrict__ deg, int* __restrict__ row_ptr,
                                              int* __restrict__ cursor) {
    __shared__ int buf[256];
    int tid = threadIdx.x;
    int base = 0;
    for (int c = 0; c < NN; c += 256) {
        int i = c + tid;
        int v = (i < NN) ? deg[i] : 0;
        buf[tid] = v;
        __syncthreads();
        for (int off = 1; off < 256; off <<= 1) {
            int t = (tid >= off) ? buf[tid - off] : 0;
            __syncthreads();
            buf[tid] += t;
            __syncthreads();
        }
        if (i < NN) {
            row_ptr[i + 1] = base + buf[tid];
            cursor[i] = base + buf[tid] - v;
        }
        __syncthreads();
        base += buf[255];
        __syncthreads();
    }
    if (tid == 0) row_ptr[0] = 0;
}

__global__ __launch_bounds__(256) void k_scatter(const int* __restrict__ dst, int* __restrict__ cursor,
                                                 int* __restrict__ csr) {
    int e = blockIdx.x * 256 + threadIdx.x;
    if (e < NE) {
        int p = atomicAdd(&cursor[dst[e]], 1);
        csr[p] = e;
    }
}

// ---------------- per-type node encoder (fp32) ----------------
__global__ __launch_bounds__(256) void k_enc(const float* __restrict__ x, const float* __restrict__ pe,
        const int* __restrict__ types,
        const float* __restrict__ w1, const float* __restrict__ b1,
        const float* __restrict__ w2, const float* __restrict__ b2,
        float* __restrict__ h_nodes) {
    int n = blockIdx.x;
    int j = threadIdx.x;
    __shared__ float inp[21];
    __shared__ float hid[256];
    if (j < 16) inp[j] = x[(size_t)n * 16 + j];
    else if (j < 21) inp[j] = pe[(size_t)n * 5 + (j - 16)];
    __syncthreads();
    int t = types[n];
    const float* W1 = w1 + (size_t)t * 21 * 256;
    float a = b1[t * 256 + j];
    #pragma unroll
    for (int i = 0; i < 21; ++i) a = fmaf(inp[i], W1[i * 256 + j], a);
    hid[j] = fmaxf(a, 0.f);
    __syncthreads();
    const float* W2 = w2 + (size_t)t * 256 * 256;
    float o = b2[t * 256 + j];
    #pragma unroll 8
    for (int k = 0; k < 256; ++k) o = fmaf(hid[k], W2[k * 256 + j], o);
    h_nodes[(size_t)n * 256 + j] = o;
}

// ---------------- small fp32 GEMM (edge encoder layer 1, K=8), relu, fp32 out ----------------
__global__ __launch_bounds__(256) void gemm64(int Mrows, int K, int Nout,
        const float* __restrict__ A0, int lda,
        const float* __restrict__ W, const float* __restrict__ bias,
        float* __restrict__ C) {
    __shared__ __align__(16) float As[16][68];
    __shared__ __align__(16) float Ws[16][64];
    int tid = threadIdx.x;
    int tx = tid & 15, ty = tid >> 4;
    int blockRow = blockIdx.x * 64;
    int ncol0 = blockIdx.y * 64;
    float acc[4][4];
    #pragma unroll
    for (int i = 0; i < 4; ++i)
        #pragma unroll
        for (int j = 0; j < 4; ++j) acc[i][j] = 0.f;

    for (int k0 = 0; k0 < K; k0 += 16) {
        #pragma unroll
        for (int i = 0; i < 4; ++i) {
            int id = tid + 256 * i;
            int kk = id & 15, r = id >> 4;
            int grow = blockRow + r;
            int k = k0 + kk;
            float v = 0.f;
            if (grow < Mrows && k < K) v = A0[(size_t)grow * lda + k];
            As[kk][r] = v;
        }
        #pragma unroll
        for (int i = 0; i < 4; ++i) {
            int id = tid + 256 * i;
            int c = id & 63, kk = id >> 6;
            int k = k0 + kk;
            Ws[kk][c] = (k < K) ? W[(size_t)k * Nout + ncol0 + c] : 0.f;
        }
        __syncthreads();
        #pragma unroll
        for (int kk = 0; kk < 16; ++kk) {
            const float4 a4 = *(const float4*)&As[kk][ty << 2];
            const float4 w4 = *(const float4*)&Ws[kk][tx << 2];
            float av[4] = {a4.x, a4.y, a4.z, a4.w};
            float wv[4] = {w4.x, w4.y, w4.z, w4.w};
            #pragma unroll
            for (int i = 0; i < 4; ++i)
                #pragma unroll
                for (int j = 0; j < 4; ++j)
                    acc[i][j] = fmaf(av[i], wv[j], acc[i][j]);
        }
        __syncthreads();
    }
    #pragma unroll
    for (int i = 0; i < 4; ++i) {
        int grow = blockRow + (ty << 2) + i;
        if (grow >= Mrows) continue;
        size_t base = (size_t)grow * Nout + ncol0 + (tx << 2);
        #pragma unroll
        for (int j = 0; j < 4; ++j)
            C[base + j] = fmaxf(acc[i][j] + bias[ncol0 + (tx << 2) + j], 0.f);
    }
}

// ---------------- main fp32 GEMM: BM=64, BN=128, BK=16, 256 threads, 4x8 per thread ----------------
// AMODE 0: A = A0[(row+rowOfsA)*lda + k]
// AMODE 2: A = concat(A0[row+rowOfsA], A1[row+rowOfsA]) (K=512, both lda 256)
// PGATH: epilogue adds Pa[gsrc[row+rowOfsA]] + Pb[gdst[row+rowOfsA]] (Nout==256 assumed)
// HASRES: after relu-position, v += resScale * ResF[crow*Nout+col]
template<int AMODE, bool RELU, bool HASRES, bool PGATH, bool HASBIAS>
__global__ __launch_bounds__(256) void gemm_f32(int Mrows, int K, int Nout,
        const float* __restrict__ A0, const float* __restrict__ A1, int lda, int rowOfsA,
        const int* __restrict__ gsrc, const int* __restrict__ gdst,
        const float* __restrict__ Pa, const float* __restrict__ Pb,
        const float* __restrict__ W, const float* __restrict__ bias,
        const float* __restrict__ ResF, float resScale, int rowOfsC,
        float* __restrict__ C) {
    __shared__ __align__(16) float As[16][68];
    __shared__ __align__(16) float Ws[16][16][10];   // [k][colgroup][8 used of 10]
    int tid = threadIdx.x;
    int blockRow = blockIdx.x * 64;
    int ncol0 = blockIdx.y * 128;
    int rg = tid >> 4, cg = tid & 15;                // compute: rows rg*4..+3, cols cg*8..+7
    int sar = tid >> 2, sak = (tid & 3) * 4;         // A staging: row, k-chunk
    int swk = tid >> 4, scg = tid & 15;              // W staging: k, col-group
    float acc[4][8];
    #pragma unroll
    for (int i = 0; i < 4; ++i)
        #pragma unroll
        for (int n = 0; n < 8; ++n) acc[i][n] = 0.f;

    for (int k0 = 0; k0 < K; k0 += 16) {
        // ---- stage A (64 x 16) ----
        {
            int arow = imin(blockRow + sar, Mrows - 1) + rowOfsA;
            float4 av;
            if (AMODE == 0) {
                av = *(const float4*)(A0 + (size_t)arow * lda + k0 + sak);
            } else {
                int k = k0 + sak;
                av = (k < 256) ? *(const float4*)(A0 + (size_t)arow * 256 + k)
                               : *(const float4*)(A1 + (size_t)arow * 256 + (k - 256));
            }
            As[sak + 0][sar] = av.x;
            As[sak + 1][sar] = av.y;
            As[sak + 2][sar] = av.z;
            As[sak + 3][sar] = av.w;
        }
        // ---- stage W (16 x 128) ----
        {
            const float* wp = W + (size_t)(k0 + swk) * Nout + ncol0 + scg * 8;
            *(float4*)&Ws[swk][scg][0] = *(const float4*)(wp + 0);
            *(float4*)&Ws[swk][scg][4] = *(const float4*)(wp + 4);
        }
        __syncthreads();
        #pragma unroll
        for (int kk = 0; kk < 16; ++kk) {
            const float4 a4 = *(const float4*)&As[kk][rg << 2];
            float av[4] = {a4.x, a4.y, a4.z, a4.w};
            const float4 w0 = *(const float4*)&Ws[kk][cg][0];
            const float4 w1 = *(const float4*)&Ws[kk][cg][4];
            float wv[8] = {w0.x, w0.y, w0.z, w0.w, w1.x, w1.y, w1.z, w1.w};
            #pragma unroll
            for (int i = 0; i < 4; ++i)
                #pragma unroll
                for (int j = 0; j < 8; ++j)
                    acc[i][j] = fmaf(av[i], wv[j], acc[i][j]);
        }
        __syncthreads();
    }
    // ---- epilogue ----
    #pragma unroll
    for (int i = 0; i < 4; ++i) {
        int grow = blockRow + (rg << 2) + i;
        if (grow >= Mrows) continue;
        size_t crow = (size_t)(grow + rowOfsC);
        int colb = ncol0 + (cg << 3);
        const float* par = nullptr;
        const float* pbr = nullptr;
        if (PGATH) {
            int e = grow + rowOfsA;
            par = Pa + (size_t)gsrc[e] * 256 + colb;
            pbr = Pb + (size_t)gdst[e] * 256 + colb;
        }
        #pragma unroll
        for (int q = 0; q < 2; ++q) {
            float v[4];
            #pragma unroll
            for (int j = 0; j < 4; ++j) v[j] = acc[i][q * 4 + j];
            if (HASBIAS) {
                const float4 b4 = *(const float4*)(bias + colb + q * 4);
                v[0] += b4.x; v[1] += b4.y; v[2] += b4.z; v[3] += b4.w;
            }
            if (PGATH) {
                const float4 pa4 = *(const float4*)(par + q * 4);
                const float4 pb4 = *(const float4*)(pbr + q * 4);
                v[0] += pa4.x + pb4.x; v[1] += pa4.y + pb4.y;
                v[2] += pa4.z + pb4.z; v[3] += pa4.w + pb4.w;
            }
            if (RELU) {
                v[0] = fmaxf(v[0], 0.f); v[1] = fmaxf(v[1], 0.f);
                v[2] = fmaxf(v[2], 0.f); v[3] = fmaxf(v[3], 0.f);
            }
            if (HASRES) {
                const float4 rv = *(const float4*)(ResF + crow * Nout + colb + q * 4);
                v[0] += resScale * rv.x; v[1] += resScale * rv.y;
                v[2] += resScale * rv.z; v[3] += resScale * rv.w;
            }
            float4 o; o.x = v[0]; o.y = v[1]; o.z = v[2]; o.w = v[3];
            *(float4*)(C + crow * Nout + colb + q * 4) = o;
        }
    }
}

// ---------------- segment-sum: m_node[n] = sum_e h_edges[e] (fp32) ----------------
__global__ __launch_bounds__(256) void k_mnode(const float* __restrict__ h_edges,
        const int* __restrict__ row_ptr, const int* __restrict__ csr, float* __restrict__ m_node) {
    int n = blockIdx.x * 4 + (threadIdx.x >> 6);
    int lane = threadIdx.x & 63;
    if (n >= NN) return;
    float a0 = 0.f, a1 = 0.f, a2 = 0.f, a3 = 0.f;
    int s = row_ptr[n], e = row_ptr[n + 1];
    for (int i = s; i < e; ++i) {
        int ed = csr[i];
        const float4 v = *(const float4*)(h_edges + (size_t)ed * 256 + (lane << 2));
        a0 += v.x; a1 += v.y; a2 += v.z; a3 += v.w;
    }
    float4 r; r.x = a0; r.y = a1; r.z = a2; r.w = a3;
    *(float4*)(m_node + (size_t)n * 256 + (lane << 2)) = r;
}

// ---------------- flash attention, split-K x4: partials (m, l, unnormalized o) ----------------
// blockIdx.y = ((g*4+h)<<2) | part ; part handles keys [part*313, min(+313, SPGc))
__global__ __launch_bounds__(256) void k_attn_part(const float* __restrict__ qkv,
        float* __restrict__ opart, float* __restrict__ mpart, float* __restrict__ lpart) {
    int y = blockIdx.y;
    int p = y & 3;
    int gh = y >> 2;
    int g = gh >> 2, h = gh & 3;
    int kb = p * 313;
    int ke = imin(kb + 313, SPGc);
    int q0 = blockIdx.x * 64;
    int tid = threadIdx.x;
    int r = tid >> 2, q4 = tid & 3;
    int d0 = q4 * 16;
    __shared__ __align__(16) float Ks[32][64];
    __shared__ __align__(16) float Vs[32][64];
    const float* base = qkv + (size_t)g * SPGc * 768;
    int my_s = q0 + r;
    bool rowok = my_s < SPGc;
    float qreg[16];
    #pragma unroll
    for (int dd = 0; dd < 16; ++dd) qreg[dd] = 0.f;
    if (rowok) {
        const float* qp = base + (size_t)my_s * 768 + h * 64 + d0;
        #pragma unroll
        for (int dd = 0; dd < 16; ++dd) qreg[dd] = qp[dd];
    }
    float m = -1e30f, l = 0.f;
    float oacc[16];
    #pragma unroll
    for (int dd = 0; dd < 16; ++dd) oacc[dd] = 0.f;

    for (int t0 = kb; t0 < ke; t0 += 32) {
        #pragma unroll
        for (int i = 0; i < 8; ++i) {
            int id = tid + 256 * i;
            int d = id & 63, jj = id >> 6;
            int s = t0 + jj;
            float kv = 0.f, vv = 0.f;
            if (s < ke) {
                const float* kp = base + (size_t)s * 768 + h * 64;
                kv = kp[256 + d];
                vv = kp[512 + d];
            }
            Ks[jj][d] = kv;
            Vs[jj][d] = vv;
        }
        __syncthreads();
        float sc[32];
        #pragma unroll
        for (int j = 0; j < 32; ++j) {
            float pq = 0.f;
            #pragma unroll
            for (int dd = 0; dd < 16; dd += 4) {
                const float4 k4 = *(const float4*)&Ks[j][d0 + dd];
                pq = fmaf(qreg[dd], k4.x, pq);
                pq = fmaf(qreg[dd + 1], k4.y, pq);
                pq = fmaf(qreg[dd + 2], k4.z, pq);
                pq = fmaf(qreg[dd + 3], k4.w, pq);
            }
            sc[j] = pq;
        }
        #pragma unroll
        for (int j = 0; j < 32; ++j) {
            float pq = sc[j];
            pq += __shfl_xor(pq, 1);
            pq += __shfl_xor(pq, 2);
            sc[j] = (t0 + j < ke) ? pq * 0.125f : -1e30f;
        }
        float mt = sc[0];
        #pragma unroll
        for (int j = 1; j < 32; ++j) mt = fmaxf(mt, sc[j]);
        float mnew = fmaxf(m, mt);
        float f = __expf(m - mnew);
        l *= f;
        #pragma unroll
        for (int dd = 0; dd < 16; ++dd) oacc[dd] *= f;
        #pragma unroll
        for (int j = 0; j < 32; ++j) {
            float pq = __expf(sc[j] - mnew);
            l += pq;
            #pragma unroll
            for (int dd = 0; dd < 16; dd += 4) {
                const float4 v4 = *(const float4*)&Vs[j][d0 + dd];
                oacc[dd]     = fmaf(pq, v4.x, oacc[dd]);
                oacc[dd + 1] = fmaf(pq, v4.y, oacc[dd + 1]);
                oacc[dd + 2] = fmaf(pq, v4.z, oacc[dd + 2]);
                oacc[dd + 3] = fmaf(pq, v4.w, oacc[dd + 3]);
            }
        }
        m = mnew;
        __syncthreads();
    }
    if (rowok) {
        size_t R = (size_t)gh * SPGc + my_s;
        float* op = opart + (R * 4 + p) * 64 + d0;
        #pragma unroll
        for (int dd = 0; dd < 16; ++dd) op[dd] = oacc[dd];
        if (q4 == 0) {
            mpart[R * 4 + p] = m;
            lpart[R * 4 + p] = l;
        }
    }
}

// ---------------- merge 4 attention partials per (g,h,s) row ----------------
__global__ __launch_bounds__(256) void k_amerge(const float* __restrict__ opart,
        const float* __restrict__ mpart, const float* __restrict__ lpart,
        float* __restrict__ obuf) {
    int R = blockIdx.x * 4 + (threadIdx.x >> 6);
    int lane = threadIdx.x & 63;
    if (R >= NROWS_A) return;
    float m0 = mpart[R * 4 + 0], m1 = mpart[R * 4 + 1];
    float m2 = mpart[R * 4 + 2], m3 = mpart[R * 4 + 3];
    float ms = fmaxf(fmaxf(m0, m1), fmaxf(m2, m3));
    float w0 = __expf(m0 - ms), w1 = __expf(m1 - ms);
    float w2 = __expf(m2 - ms), w3 = __expf(m3 - ms);
    float l = w0 * lpart[R * 4 + 0] + w1 * lpart[R * 4 + 1]
            + w2 * lpart[R * 4 + 2] + w3 * lpart[R * 4 + 3];
    const float* ob = opart + (size_t)R * 4 * 64 + lane;
    float o = w0 * ob[0] + w1 * ob[64] + w2 * ob[128] + w3 * ob[192];
    int gh = R / SPGc, s = R % SPGc;
    int g = gh >> 2, h = gh & 3;
    obuf[((size_t)(g * SPGc + s)) * 256 + h * 64 + lane] = o / l;
}

// ---------------- per-type decoder (fp32 in) ----------------
__global__ __launch_bounds__(256) void k_dec(const float* __restrict__ h, const int* __restrict__ types,
        const float* __restrict__ w1, const float* __restrict__ b1,
        const float* __restrict__ w2, const float* __restrict__ b2,
        float* __restrict__ out) {
    int n = blockIdx.x;
    int j = threadIdx.x;
    __shared__ float hrow[256];
    __shared__ float dhid[256];
    hrow[j] = h[(size_t)n * 256 + j];
    __syncthreads();
    int t = types[n];
    const float* W1 = w1 + (size_t)t * 256 * 256;
    float a = b1[t * 256 + j];
    #pragma unroll 8
    for (int k = 0; k < 256; ++k) a = fmaf(hrow[k], W1[k * 256 + j], a);
    dhid[j] = fmaxf(a, 0.f);
    __syncthreads();
    int lane = j & 63, w = j >> 6;
    const float* W2 = w2 + (size_t)t * 256 * 4;
    float p = 0.f;
    #pragma unroll
    for (int q = 0; q < 4; ++q) {
        int kk = lane + 64 * q;
        p = fmaf(dhid[kk], W2[kk * 4 + w], p);
    }
    #pragma unroll
    for (int o2 = 32; o2 > 0; o2 >>= 1) p += __shfl_down(p, o2);
    if (lane == 0) out[(size_t)n * 4 + w] = p + b2[t * 4 + w];
}

extern "C" void kernel_launch(void* const* d_in, const int* in_sizes, int n_in,
                              void* d_out, int out_size, void* d_ws, size_t ws_size,
                              hipStream_t stream) {
    const float* x         = (const float*)d_in[0];
    const float* pe        = (const float*)d_in[1];
    const float* edge_attr = (const float*)d_in[2];
    const int*   eidx      = (const int*)d_in[3];
    const float* enc_w1 = (const float*)d_in[5];
    const float* enc_b1 = (const float*)d_in[6];
    const float* enc_w2 = (const float*)d_in[7];
    const float* enc_b2 = (const float*)d_in[8];
    const float* ee_w1  = (const float*)d_in[9];
    const float* ee_b1  = (const float*)d_in[10];
    const float* ee_w2  = (const float*)d_in[11];
    const float* ee_b2  = (const float*)d_in[12];
    const float* eu_w1  = (const float*)d_in[13];
    const float* eu_b1  = (const float*)d_in[14];
    const float* eu_w2  = (const float*)d_in[15];
    const float* eu_b2  = (const float*)d_in[16];
    const float* nu_w1  = (const float*)d_in[17];
    const float* nu_b1  = (const float*)d_in[18];
    const float* nu_w2  = (const float*)d_in[19];
    const float* nu_b2  = (const float*)d_in[20];
    const float* qkv_w  = (const float*)d_in[21];
    const float* qkv_b  = (const float*)d_in[22];
    const float* out_w  = (const float*)d_in[23];
    const float* out_b  = (const float*)d_in[24];
    const float* fu_w1  = (const float*)d_in[25];
    const float* fu_b1  = (const float*)d_in[26];
    const float* fu_w2  = (const float*)d_in[27];
    const float* fu_b2  = (const float*)d_in[28];
    const float* dec_w1 = (const float*)d_in[29];
    const float* dec_b1 = (const float*)d_in[30];
    const float* dec_w2 = (const float*)d_in[31];
    const float* dec_b2 = (const float*)d_in[32];

    const int* src  = eidx;
    const int* dstp = eidx + NE;

    float* ws = (float*)d_ws;
    float* h_edges = ws;                       // 25.6M f  (reused for attn partials later)
    float* big     = ws + 25600000;            // 11.52M f region
    float* h_nodes = ws + 37120000;            // 2.56M f
    float* mn_ob   = ws + 39680000;            // 2.56M f (m_node -> obuf -> hfused)
    float* nhid    = ws + 42240000;            // 2.56M f
    int* ibase   = (int*)(ws + 44800000);
    int* types   = ibase;
    int* deg     = ibase + NN;
    int* row_ptr = deg + NN;
    int* cursor  = row_ptr + NN + 1;
    int* csr     = cursor + NN;

    // big region overlays (phase-disjoint):
    float* ehid = big;                 // [ECHK][256] = 6.4M f (layer phase)
    float* Pa   = big + 6400000;       // 2.56M f (layer phase)
    float* Pb   = big + 8960000;       // 2.56M f (layer phase)
    float* qkvf = big;                 // [NN][768] = 7.68M f (attention phase)
    float* fin  = big + 7680000;       // 2.56M f (fusion phase)

    // attention partials overlay h_edges (dead after last k_mnode):
    float* opart = h_edges;                       // 40000*4*64 = 10.24M f
    float* mpart = h_edges + 10240000;            // 160K f
    float* lpart = h_edges + 10400000;            // 160K f

    hipMemsetAsync(deg, 0, NN * sizeof(int), stream);
    k_types<<<(NN + 255) / 256, 256, 0, stream>>>(x, types);
    k_hist<<<(NE + 255) / 256, 256, 0, stream>>>(dstp, deg);
    k_scan<<<1, 256, 0, stream>>>(deg, row_ptr, cursor);
    k_scatter<<<(NE + 255) / 256, 256, 0, stream>>>(dstp, cursor, csr);

    k_enc<<<NN, 256, 0, stream>>>(x, pe, types, enc_w1, enc_b1, enc_w2, enc_b2, h_nodes);

    dim3 gE((ECHK + 63) / 64, 2);
    dim3 gN((NN + 63) / 64, 2);

    // edge encoder (chunked): ehid = relu(edge_attr@ee_w1+b); h_edges = ehid@ee_w2+b
    for (int c0 = 0; c0 < NE; c0 += ECHK) {
        gemm64<<<dim3((ECHK + 63) / 64, 4), 256, 0, stream>>>(ECHK, 8, 256,
            edge_attr + (size_t)c0 * 8, 8, ee_w1, ee_b1, ehid);
        gemm_f32<0, false, false, false, true><<<gE, 256, 0, stream>>>(ECHK, 256, 256,
            ehid, nullptr, 256, 0, nullptr, nullptr, nullptr, nullptr,
            ee_w2, ee_b2, nullptr, 0.f, c0, h_edges);
    }

    // message-passing layers
    for (int l = 0; l < NL; ++l) {
        const float* W1 = eu_w1 + (size_t)l * 768 * 256;
        // Pa = h_nodes @ W1[0:256], Pb = h_nodes @ W1[256:512]   (no bias, no relu)
        gemm_f32<0, false, false, false, false><<<gN, 256, 0, stream>>>(NN, 256, 256,
            h_nodes, nullptr, 256, 0, nullptr, nullptr, nullptr, nullptr,
            W1, nullptr, nullptr, 0.f, 0, Pa);
        gemm_f32<0, false, false, false, false><<<gN, 256, 0, stream>>>(NN, 256, 256,
            h_nodes, nullptr, 256, 0, nullptr, nullptr, nullptr, nullptr,
            W1 + 65536, nullptr, nullptr, 0.f, 0, Pb);
        for (int c0 = 0; c0 < NE; c0 += ECHK) {
            // ehid = relu(h_edges@W1c + Pa[src] + Pb[dst] + b1)
            gemm_f32<0, true, false, true, true><<<gE, 256, 0, stream>>>(ECHK, 256, 256,
                h_edges, nullptr, 256, c0, src, dstp, Pa, Pb,
                W1 + 131072, eu_b1 + l * 256, nullptr, 0.f, 0, ehid);
            // h_edges += ehid@W2 + b2
            gemm_f32<0, false, true, false, true><<<gE, 256, 0, stream>>>(ECHK, 256, 256,
                ehid, nullptr, 256, 0, nullptr, nullptr, nullptr, nullptr,
                eu_w2 + (size_t)l * 65536, eu_b2 + l * 256, h_edges, 1.f, c0, h_edges);
        }
        k_mnode<<<(NN + 3) / 4, 256, 0, stream>>>(h_edges, row_ptr, csr, mn_ob);
        // nhid = relu(concat(h_nodes, m_node)@nu_w1 + b)
        gemm_f32<2, true, false, false, true><<<gN, 256, 0, stream>>>(NN, 512, 256,
            h_nodes, mn_ob, 256, 0, nullptr, nullptr, nullptr, nullptr,
            nu_w1 + (size_t)l * 131072, nu_b1 + l * 256, nullptr, 0.f, 0, nhid);
        // h_nodes += nhid@nu_w2 + b
        gemm_f32<0, false, true, false, true><<<gN, 256, 0, stream>>>(NN, 256, 256,
            nhid, nullptr, 256, 0, nullptr, nullptr, nullptr, nullptr,
            nu_w2 + (size_t)l * 65536, nu_b2 + l * 256, h_nodes, 1.f, 0, h_nodes);
    }

    // qkv projection (fp32)
    gemm_f32<0, false, false, false, true><<<dim3((NN + 63) / 64, 6), 256, 0, stream>>>(NN, 256, 768,
        h_nodes, nullptr, 256, 0, nullptr, nullptr, nullptr, nullptr,
        qkv_w, qkv_b, nullptr, 0.f, 0, qkvf);

    // attention: 4-way split-K partials + merge
    dim3 ga((SPGc + 63) / 64, NG * 4 * 4);
    k_attn_part<<<ga, 256, 0, stream>>>(qkvf, opart, mpart, lpart);
    k_amerge<<<(NROWS_A + 3) / 4, 256, 0, stream>>>(opart, mpart, lpart, mn_ob);

    // fin = obuf@out_w + out_b + 2*h_nodes ; nhid = relu(fin@fu_w1+b) ; hfused = nhid@fu_w2+b
    gemm_f32<0, false, true, false, true><<<gN, 256, 0, stream>>>(NN, 256, 256,
        mn_ob, nullptr, 256, 0, nullptr, nullptr, nullptr, nullptr,
        out_w, out_b, h_nodes, 2.f, 0, fin);
    gemm_f32<0, true, false, false, true><<<gN, 256, 0, stream>>>(NN, 256, 256,
        fin, nullptr, 256, 0, nullptr, nullptr, nullptr, nullptr,
        fu_w1, fu_b1, nullptr, 0.f, 0, nhid);
    gemm_f32<0, false, false, false, true><<<gN, 256, 0, stream>>>(NN, 256, 256,
        nhid, nullptr, 256, 0, nullptr, nullptr, nullptr, nullptr,
        fu_w2, fu_b2, nullptr, 0.f, 0, mn_ob);

    k_dec<<<NN, 256, 0, stream>>>(mn_ob, types, dec_w1, dec_b1, dec_w2, dec_b2, (float*)d_out);
}